// Round 9
// baseline (2083.375 us; speedup 1.0000x reference)
//
#include <hip/hip_runtime.h>
#include <stdint.h>

#define B_ 1024
#define F_ 4
#define M_ 512
#define D_ 8192
#define ITERS_ 10
#define DW_ 128      // D/64 u64 words per D-vector
#define SMSZ 24576   // one staging buffer: 3 arrays x 128 rows x 64 B

typedef unsigned long long u64;
typedef unsigned int u32;
typedef unsigned short u16;
typedef signed char i8;

typedef int i32x4 __attribute__((ext_vector_type(4)));

struct Flags { u32 done; u32 k; u32 conv[ITERS_]; };

__device__ inline void gload_lds16(const void* g, void* l){
  __builtin_amdgcn_global_load_lds(
      (const __attribute__((address_space(1))) void*)g,
      (__attribute__((address_space(3))) void*)l, 16, 0, 0);
}

__device__ inline bool conv_prefix_done(const u32* conv, int iter){
  bool d = false;
  for (int j = 0; j < iter; ++j) d |= (conv[j] != 0u);
  return d;
}

// sign-bit pack (bit=1 => negative) via wave ballot; one u64 per 64 floats
__global__ void k_bitify(const float* __restrict__ src, u64* __restrict__ dst){
  long gid = (long)blockIdx.x * 256 + threadIdx.x;
  float v = src[gid];
  u64 m = __ballot(v < 0.0f);
  if ((threadIdx.x & 63) == 0) dst[gid >> 6] = m;
}

// init_est is broadcast over b by construction; bitify row b=0 only + Flags init
__global__ void k_bitify0(const float* __restrict__ init_est, u64* __restrict__ tmp0,
                          Flags* fl){
  long gid = (long)blockIdx.x * 256 + threadIdx.x;   // over F_*D_
  float v = init_est[gid];
  u64 m = __ballot(v < 0.0f);
  if ((threadIdx.x & 63) == 0) tmp0[gid >> 6] = m;
  if (blockIdx.x == 0){
    if (threadIdx.x == 0){ fl->done = 0; fl->k = 0; }
    if (threadIdx.x < ITERS_) fl->conv[threadIdx.x] = 1u;
  }
}

// broadcast tmp0[f][w] to estbits[b][f][w] for all b
__global__ void k_bcast(const u64* __restrict__ tmp0, u64* __restrict__ estbits){
  long gid = (long)blockIdx.x * 256 + threadIdx.x;   // over B_*F_*DW_
  estbits[gid] = tmp0[gid & (F_*DW_ - 1)];
}

// one pass over cb: cbbT[f][w][m] (bit-packed) AND cbT8[f][d][m] (i8 +-1)
__global__ void k_cb_prep(const float* __restrict__ cb, u64* __restrict__ cbbT,
                          i8* __restrict__ cbT8){
  __shared__ i8 tile[64][68];
  int bx = blockIdx.x;
  int f = bx >> 10;
  int r = bx & 1023;
  int mt = r >> 7, dt = r & 127;
  for (int it = 0; it < 16; ++it){
    int lid = threadIdx.x + it*256;
    int i = lid >> 6, j = lid & 63;   // i = m-local (wave-uniform), j = d-local = lane
    float v = cb[((long)(f*M_ + mt*64 + i))*D_ + dt*64 + j];
    tile[j][i] = (v < 0.0f) ? (i8)-1 : (i8)1;
    u64 msk = __ballot(v < 0.0f);     // bit L = sign at d = dt*64 + L
    if (j == 0) cbbT[((long)(f*DW_ + dt))*M_ + mt*64 + i] = msk;
  }
  __syncthreads();
  for (int it = 0; it < 4; ++it){
    int lid = threadIdx.x + it*256;   // 1024 jobs: 64 d x 16 m-groups
    int dd = lid >> 4, mg = lid & 15;
    u32 p = (u32)(unsigned char)tile[dd][mg*4+0]
          | ((u32)(unsigned char)tile[dd][mg*4+1] << 8)
          | ((u32)(unsigned char)tile[dd][mg*4+2] << 16)
          | ((u32)(unsigned char)tile[dd][mg*4+3] << 24);
    *(u32*)(cbT8 + ((long)(f*D_ + dt*64 + dd))*M_ + mt*64 + mg*4) = p;
  }
}

// forward: nb = in ^ (xor of other three est); v[m] = 4096 - popcount(nb ^ cb[m])
// 16 b-rows per block: each cb word loaded once, reused 16x from LDS/regs.
__global__ __launch_bounds__(128) void k_forward(
    const u64* __restrict__ inbits, const u64* __restrict__ estbits,
    const u64* __restrict__ cbbT, i8* __restrict__ Aq, i8* __restrict__ Ar,
    const Flags* __restrict__ fl, int iter){
  if (conv_prefix_done(fl->conv, iter)) return;
  __shared__ u64 nbs[16][DW_];
  int f  = blockIdx.z;
  int m0 = blockIdx.y * 128;
  int b0 = blockIdx.x * 16;
  for (int idx = threadIdx.x; idx < 16*DW_; idx += 128){
    int bb = idx >> 7, w = idx & 127;
    const u64* eb = estbits + (long)(b0 + bb)*F_*DW_;
    u64 all = eb[w] ^ eb[DW_+w] ^ eb[2*DW_+w] ^ eb[3*DW_+w];
    nbs[bb][w] = inbits[(long)(b0 + bb)*DW_ + w] ^ all ^ eb[f*DW_ + w];
  }
  __syncthreads();
  int m = m0 + threadIdx.x;
  int acc[16];
  #pragma unroll
  for (int bb = 0; bb < 16; ++bb) acc[bb] = 0;
  const u64* cbf = cbbT + (long)f*DW_*M_ + m;
  for (int w = 0; w < DW_; ++w){
    u64 c = cbf[(long)w*M_];
    #pragma unroll
    for (int bb = 0; bb < 16; ++bb) acc[bb] += (int)__popcll(nbs[bb][w] ^ c);
  }
  #pragma unroll
  for (int bb = 0; bb < 16; ++bb){
    int v = 4096 - acc[bb];
    int r = ((v + 32) & 63) - 32;
    int q = (v - r) >> 6;
    long base = ((long)(f*B_ + b0 + bb))*M_ + m;
    Aq[base] = (i8)q;
    Ar[base] = (i8)r;
  }
}

// backward: y[b][d] = sum q*(64c) + sum r*c, single i32 acc, exact. i8 MFMA
// 16x16x64, double-buffered DMA pipeline (1 barrier/round, latency overlapped
// with compute), ballot-based epilogue (no LDS, no extra barriers).
__global__ __launch_bounds__(256) void k_backward_mfma8(
    const i8* __restrict__ Aq, const i8* __restrict__ Ar, const i8* __restrict__ cbT8,
    u64* __restrict__ estbits, Flags* fl, int iter){
  if (conv_prefix_done(fl->conv, iter)) return;
  __shared__ __attribute__((aligned(16))) i8 smem[2*SMSZ]; // 49152 B
  int f = blockIdx.z, bt = blockIdx.y, dt = blockIdx.x;
  int b0 = bt*128, d0 = dt*128;
  int tid = threadIdx.x;
  int wv = tid >> 6, lane = tid & 63, l16 = lane & 15, quad = lane >> 4;
  int rl = lane >> 2, pl = lane & 3;   // DMA: 4 lanes per 64B row

  i32x4 zero = {0, 0, 0, 0};
  i32x4 acc[2][8];
  #pragma unroll
  for (int i = 0; i < 2; ++i)
    #pragma unroll
    for (int j = 0; j < 8; ++j) acc[i][j] = zero;

  const i8* Aqg = Aq + ((long)f*B_ + b0)*M_;
  const i8* Arg = Ar + ((long)f*B_ + b0)*M_;
  const i8* Bg  = cbT8 + ((long)f*D_ + d0)*M_;

  // per-wave DMA plan: 24 issues = 3 arrays x 8 windows(16 rows); wave takes 6.
  // lane fetches global chunk (pl ^ ((rl>>1)&3)) so LDS slot c' holds chunk c'^swz.
  const i8* gsrc[6];
  i8* lbase[6];
  int swz = (rl >> 1) & 3;
  #pragma unroll
  for (int j2 = 0; j2 < 6; ++j2){
    int i = j2*4 + wv;
    int t = i >> 3, j = i & 7;
    const i8* src = (t == 0) ? Aqg : (t == 1) ? Arg : Bg;
    gsrc[j2]  = src + (long)(j*16 + rl)*M_ + ((pl ^ swz) << 4);
    lbase[j2] = smem + t*8192 + j*1024;   // HW adds lane*16B
  }

  // prologue: issue kt=0 into buffer 0
  #pragma unroll
  for (int j2 = 0; j2 < 6; ++j2)
    gload_lds16(gsrc[j2], lbase[j2]);

  for (int kt = 0; kt < 8; ++kt){
    __syncthreads();   // drains buffer[kt&1]'s DMA; frees buffer[(kt+1)&1] reads
    if (kt < 7){
      int nb = (kt + 1) & 1, k0 = (kt + 1)*64;
      #pragma unroll
      for (int j2 = 0; j2 < 6; ++j2)
        gload_lds16(gsrc[j2] + k0, lbase[j2] + nb*SMSZ);
    }
    const i8* sb = smem + (kt & 1)*SMSZ;
    i32x4 aq[2], ar[2];
    #pragma unroll
    for (int rt = 0; rt < 2; ++rt){
      int row = wv*32 + rt*16 + l16;     // A[m=lane&15][k=quad*16+j]
      int c = (quad ^ ((row >> 1) & 3)) << 4;
      aq[rt] = *(const i32x4*)(sb +        row*64 + c);
      ar[rt] = *(const i32x4*)(sb + 8192 + row*64 + c);
    }
    #pragma unroll
    for (int ct = 0; ct < 8; ++ct){
      int rowB = ct*16 + l16;            // B[k=quad*16+j][n=lane&15] via B^T tile
      int c = (quad ^ ((rowB >> 1) & 3)) << 4;
      i32x4 bb = *(const i32x4*)(sb + 16384 + rowB*64 + c);
      i32x4 bb64;
      #pragma unroll
      for (int g = 0; g < 4; ++g)
        bb64[g] = (int)(((u32)bb[g] << 6) & 0xC0C0C0C0u);   // 64*c, exact for c=+-1
      #pragma unroll
      for (int rt = 0; rt < 2; ++rt){
        acc[rt][ct] = __builtin_amdgcn_mfma_i32_16x16x64_i8(aq[rt], bb64, acc[rt][ct], 0, 0, 0);
        acc[rt][ct] = __builtin_amdgcn_mfma_i32_16x16x64_i8(ar[rt], bb,   acc[rt][ct], 0, 0, 0);
      }
    }
  }

  // ballot epilogue: C/D layout col=lane&15, row=quad*4+reg. ballot bit(16q+t)
  // = sign at (row q*4+r, col ct*16+t). Word(row, pw) = 4 stitched 16b pieces.
  u32 mymiss = 0;
  int q3 = (lane >> 1) & 3, pw = lane & 1;
  #pragma unroll
  for (int rt = 0; rt < 2; ++rt){
    #pragma unroll
    for (int r = 0; r < 4; ++r){
      u64 lo[4], hi[4];
      #pragma unroll
      for (int c = 0; c < 4; ++c){
        lo[c] = __ballot(acc[rt][c][r]     < 0);
        hi[c] = __ballot(acc[rt][4 + c][r] < 0);
      }
      u64 word = 0;
      #pragma unroll
      for (int c = 0; c < 4; ++c){
        u64 sel = pw ? hi[c] : lo[c];
        word |= ((sel >> (16*q3)) & 0xFFFFull) << (16*c);
      }
      u32 flag = 0;
      if (lane < 8){
        int row = wv*32 + rt*16 + q3*4 + r;
        long addr = ((long)(b0 + row)*F_ + f)*DW_ + (dt*2 + pw);
        u64 old = estbits[addr];
        estbits[addr] = word;
        flag = (old != word) ? 1u : 0u;
      }
      mymiss |= (u32)(__ballot(flag != 0) != 0ull);
    }
  }
  if (lane == 0 && mymiss) atomicAnd(&fl->conv[iter], 0u);
}

// final: outcome = argmax_m |sim|, first-occurrence ties (exact integers).
__global__ __launch_bounds__(256) void k_outcome(
    const u64* __restrict__ estbits, const u64* __restrict__ cbbT,
    const Flags* __restrict__ fl, float* __restrict__ out){
  __shared__ u64 es[8][DW_];
  __shared__ int redv[4][8], redi[4][8];
  int f = blockIdx.y, b0 = blockIdx.x * 8;
  int tid = threadIdx.x, wv = tid >> 6, lane = tid & 63;
  for (int idx = tid; idx < 8*DW_; idx += 256){
    int bb = idx >> 7, w = idx & 127;
    es[bb][w] = estbits[((long)(b0 + bb)*F_ + f)*DW_ + w];
  }
  __syncthreads();
  const u64* cbf = cbbT + (long)f*DW_*M_;
  int m0 = tid, m1 = tid + 256;
  int acc0[8], acc1[8];
  #pragma unroll
  for (int bb = 0; bb < 8; ++bb){ acc0[bb] = 0; acc1[bb] = 0; }
  for (int w = 0; w < DW_; ++w){
    u64 c0 = cbf[(long)w*M_ + m0];
    u64 c1 = cbf[(long)w*M_ + m1];
    #pragma unroll
    for (int bb = 0; bb < 8; ++bb){
      u64 e = es[bb][w];
      acc0[bb] += (int)__popcll(e ^ c0);
      acc1[bb] += (int)__popcll(e ^ c1);
    }
  }
  int bv[8], bi[8];
  #pragma unroll
  for (int bb = 0; bb < 8; ++bb){
    int a0 = 4096 - acc0[bb]; if (a0 < 0) a0 = -a0;
    int a1 = 4096 - acc1[bb]; if (a1 < 0) a1 = -a1;
    bv[bb] = a0; bi[bb] = m0;
    if (a1 > a0){ bv[bb] = a1; bi[bb] = m1; }   // tie keeps lower m
  }
  for (int off = 32; off; off >>= 1){
    #pragma unroll
    for (int bb = 0; bb < 8; ++bb){
      int ov = __shfl_xor(bv[bb], off, 64);
      int oi = __shfl_xor(bi[bb], off, 64);
      if (ov > bv[bb] || (ov == bv[bb] && oi < bi[bb])){ bv[bb] = ov; bi[bb] = oi; }
    }
  }
  if (lane == 0)
    #pragma unroll
    for (int bb = 0; bb < 8; ++bb){ redv[wv][bb] = bv[bb]; redi[wv][bb] = bi[bb]; }
  __syncthreads();
  if (tid < 8){
    int v0 = redv[0][tid], i0 = redi[0][tid];
    for (int w = 1; w < 4; ++w){
      int v = redv[w][tid], i = redi[w][tid];
      if (v > v0 || (v == v0 && i < i0)){ v0 = v; i0 = i; }
    }
    out[(long)(b0 + tid)*F_ + f] = (float)i0;
  }
  if (blockIdx.x == 0 && f == 0 && tid == 0){
    int k = ITERS_;
    for (int j = 0; j < ITERS_; ++j) if (fl->conv[j]){ k = j + 1; break; }
    out[B_*F_] = (float)k;
  }
}

__global__ void k_unpack(const u64* __restrict__ estbits, float* __restrict__ out){
  long gid = (long)blockIdx.x*256 + threadIdx.x;   // over B*F*D/4
  int bf = (int)(gid >> 11);
  int d4 = (int)(gid & 2047);
  u64 word = estbits[(long)bf*DW_ + (d4 >> 4)];
  u32 nib = (u32)(word >> ((d4 & 15) * 4)) & 0xFu;
  long base = (long)(B_*F_ + 1) + (long)bf*D_ + (long)d4*4;
  out[base+0] = (nib & 1u) ? -1.0f : 1.0f;
  out[base+1] = (nib & 2u) ? -1.0f : 1.0f;
  out[base+2] = (nib & 4u) ? -1.0f : 1.0f;
  out[base+3] = (nib & 8u) ? -1.0f : 1.0f;
}

extern "C" void kernel_launch(void* const* d_in, const int* in_sizes, int n_in,
                              void* d_out, int out_size, void* d_ws, size_t ws_size,
                              hipStream_t stream){
  const float* input    = (const float*)d_in[0];
  const float* init_est = (const float*)d_in[1];
  const float* cb       = (const float*)d_in[2];
  char* ws   = (char*)d_ws;
  char* outc = (char*)d_out;

  size_t off = 0;
  Flags* fl = (Flags*)(ws); off = 1024;
  u64* tmp0    = (u64*)(ws + off); off += (size_t)F_*DW_*8;        // 4 KB
  off = (off + 1023) & ~size_t(1023);
  u64* inbits  = (u64*)(ws + off); off += (size_t)B_*DW_*8;        // 1 MB
  u64* estbits = (u64*)(ws + off); off += (size_t)B_*F_*DW_*8;     // 4 MB
  u64* cbbT    = (u64*)(ws + off); off += (size_t)F_*DW_*M_*8;     // 2 MB
  size_t big = (size_t)F_*D_*M_ + 2*(size_t)F_*B_*M_;              // 16 MB + 4 MB
  i8 *cbT8, *Aq, *Ar;
  if (ws_size >= off + big + 1024){
    cbT8 = (i8*)(ws + off); off += (size_t)F_*D_*M_;
    Aq   = (i8*)(ws + off); off += (size_t)F_*B_*M_;
    Ar   = (i8*)(ws + off); off += (size_t)F_*B_*M_;
  } else {
    // d_out is 33558529 float32 = 128.02 MiB; est chunk spans [16388, 134234116).
    // Park scratch high — only the final k_unpack overwrites it, after last use.
    cbT8 = (i8*)(outc + (80ull << 20));    // 80..96 MiB
    Aq   = (i8*)(outc + (100ull << 20));   // 100..102 MiB
    Ar   = (i8*)(outc + (104ull << 20));   // 104..106 MiB
  }

  k_bitify0<<<(F_*D_)/256, 256, 0, stream>>>(init_est, tmp0, fl);
  k_bcast<<<(B_*F_*DW_)/256, 256, 0, stream>>>(tmp0, estbits);
  k_bitify<<<(B_*(long)D_)/256, 256, 0, stream>>>(input, inbits);
  k_cb_prep<<<4096, 256, 0, stream>>>(cb, cbbT, cbT8);

  for (int it = 0; it < ITERS_; ++it){
    k_forward<<<dim3(B_/16, M_/128, F_), 128, 0, stream>>>(inbits, estbits, cbbT, Aq, Ar, fl, it);
    k_backward_mfma8<<<dim3(D_/128, B_/128, F_), 256, 0, stream>>>(Aq, Ar, cbT8, estbits, fl, it);
  }

  k_outcome<<<dim3(B_/8, F_), 256, 0, stream>>>(estbits, cbbT, fl, (float*)d_out);
  k_unpack<<<((long)B_*F_*D_/4)/256, 256, 0, stream>>>(estbits, (float*)d_out);
}

// Round 10
// 1933.269 us; speedup vs baseline: 1.0776x; 1.0776x over previous
//
#include <hip/hip_runtime.h>
#include <stdint.h>

#define B_ 1024
#define F_ 4
#define M_ 512
#define D_ 8192
#define ITERS_ 10
#define DW_ 128      // D/64 u64 words per D-vector
#define SMSZ 24576   // one staging buffer: 3 arrays x 128 rows x 64 B

typedef unsigned long long u64;
typedef unsigned int u32;
typedef unsigned short u16;
typedef signed char i8;

typedef int i32x4 __attribute__((ext_vector_type(4)));

struct Flags { u32 done; u32 k; u32 conv[ITERS_]; };

__device__ inline void gload_lds16(const void* g, void* l){
  __builtin_amdgcn_global_load_lds(
      (const __attribute__((address_space(1))) void*)g,
      (__attribute__((address_space(3))) void*)l, 16, 0, 0);
}

__device__ inline bool conv_prefix_done(const u32* conv, int iter){
  bool d = false;
  for (int j = 0; j < iter; ++j) d |= (conv[j] != 0u);
  return d;
}

// sign-bit pack (bit=1 => negative) via wave ballot; one u64 per 64 floats
__global__ void k_bitify(const float* __restrict__ src, u64* __restrict__ dst){
  long gid = (long)blockIdx.x * 256 + threadIdx.x;
  float v = src[gid];
  u64 m = __ballot(v < 0.0f);
  if ((threadIdx.x & 63) == 0) dst[gid >> 6] = m;
}

// init_est is broadcast over b by construction; bitify row b=0 only + Flags init
__global__ void k_bitify0(const float* __restrict__ init_est, u64* __restrict__ tmp0,
                          Flags* fl){
  long gid = (long)blockIdx.x * 256 + threadIdx.x;   // over F_*D_
  float v = init_est[gid];
  u64 m = __ballot(v < 0.0f);
  if ((threadIdx.x & 63) == 0) tmp0[gid >> 6] = m;
  if (blockIdx.x == 0){
    if (threadIdx.x == 0){ fl->done = 0; fl->k = 0; }
    if (threadIdx.x < ITERS_) fl->conv[threadIdx.x] = 1u;
  }
}

// broadcast tmp0[f][w] to estbits[b][f][w] for all b
__global__ void k_bcast(const u64* __restrict__ tmp0, u64* __restrict__ estbits){
  long gid = (long)blockIdx.x * 256 + threadIdx.x;   // over B_*F_*DW_
  estbits[gid] = tmp0[gid & (F_*DW_ - 1)];
}

// one pass over cb: cbbT[f][w][m] (bit-packed) AND cbT8[f][d][m] (i8 +-1)
__global__ void k_cb_prep(const float* __restrict__ cb, u64* __restrict__ cbbT,
                          i8* __restrict__ cbT8){
  __shared__ i8 tile[64][68];
  int bx = blockIdx.x;
  int f = bx >> 10;
  int r = bx & 1023;
  int mt = r >> 7, dt = r & 127;
  for (int it = 0; it < 16; ++it){
    int lid = threadIdx.x + it*256;
    int i = lid >> 6, j = lid & 63;   // i = m-local (wave-uniform), j = d-local = lane
    float v = cb[((long)(f*M_ + mt*64 + i))*D_ + dt*64 + j];
    tile[j][i] = (v < 0.0f) ? (i8)-1 : (i8)1;
    u64 msk = __ballot(v < 0.0f);     // bit L = sign at d = dt*64 + L
    if (j == 0) cbbT[((long)(f*DW_ + dt))*M_ + mt*64 + i] = msk;
  }
  __syncthreads();
  for (int it = 0; it < 4; ++it){
    int lid = threadIdx.x + it*256;   // 1024 jobs: 64 d x 16 m-groups
    int dd = lid >> 4, mg = lid & 15;
    u32 p = (u32)(unsigned char)tile[dd][mg*4+0]
          | ((u32)(unsigned char)tile[dd][mg*4+1] << 8)
          | ((u32)(unsigned char)tile[dd][mg*4+2] << 16)
          | ((u32)(unsigned char)tile[dd][mg*4+3] << 24);
    *(u32*)(cbT8 + ((long)(f*D_ + dt*64 + dd))*M_ + mt*64 + mg*4) = p;
  }
}

// forward: nb = in ^ (xor of other three est); v[m] = 4096 - popcount(nb ^ cb[m])
// 8 b-rows per block, 128 threads (one m each). Flat XCD-aware grid:
// id = (f*4+mt) + 16*bt  ->  blocks sharing the cb m-slice have equal id%8
// (same XCD; 256 KB cb-slice per XCD stays L2-hot across all bt).
__global__ __launch_bounds__(128) void k_forward(
    const u64* __restrict__ inbits, const u64* __restrict__ estbits,
    const u64* __restrict__ cbbT, i8* __restrict__ Aq, i8* __restrict__ Ar,
    const Flags* __restrict__ fl, int iter){
  if (conv_prefix_done(fl->conv, iter)) return;
  __shared__ u64 nbs[8][DW_];
  int id = blockIdx.x;
  int bt = id >> 4;
  int rr = id & 15;
  int f  = rr >> 2;
  int mt = rr & 3;
  int m0 = mt * 128;
  int b0 = bt * 8;
  for (int idx = threadIdx.x; idx < 8*DW_; idx += 128){
    int bb = idx >> 7, w = idx & 127;
    const u64* eb = estbits + (long)(b0 + bb)*F_*DW_;
    u64 all = eb[w] ^ eb[DW_+w] ^ eb[2*DW_+w] ^ eb[3*DW_+w];
    nbs[bb][w] = inbits[(long)(b0 + bb)*DW_ + w] ^ all ^ eb[f*DW_ + w];
  }
  __syncthreads();
  int m = m0 + threadIdx.x;
  int acc[8];
  #pragma unroll
  for (int bb = 0; bb < 8; ++bb) acc[bb] = 0;
  const u64* cbf = cbbT + (long)f*DW_*M_ + m;
  for (int w = 0; w < DW_; ++w){
    u64 c = cbf[(long)w*M_];
    #pragma unroll
    for (int bb = 0; bb < 8; ++bb) acc[bb] += (int)__popcll(nbs[bb][w] ^ c);
  }
  #pragma unroll
  for (int bb = 0; bb < 8; ++bb){
    int v = 4096 - acc[bb];
    int r = ((v + 32) & 63) - 32;
    int q = (v - r) >> 6;
    long base = ((long)(f*B_ + b0 + bb))*M_ + m;
    Aq[base] = (i8)q;
    Ar[base] = (i8)r;
  }
}

// backward: y[b][d] = sum q*(64c) + sum r*c, single i32 acc, exact. i8 MFMA
// 16x16x64, double-buffered DMA, ballot epilogue. Flat XCD-aware grid:
// id = (f*64+dt) + 256*bt -> all 8 bt-blocks sharing a B tile have equal id%8
// (same XCD); per-XCD B footprint = 2 MB < 4 MB L2, so bt=0 warms it and
// bt=1..7 hit L2 instead of L3/HBM.
__global__ __launch_bounds__(256) void k_backward_mfma8(
    const i8* __restrict__ Aq, const i8* __restrict__ Ar, const i8* __restrict__ cbT8,
    u64* __restrict__ estbits, Flags* fl, int iter){
  if (conv_prefix_done(fl->conv, iter)) return;
  __shared__ __attribute__((aligned(16))) i8 smem[2*SMSZ]; // 49152 B
  int id = blockIdx.x;
  int bt = id >> 8;
  int rr = id & 255;
  int f  = rr >> 6;
  int dt = rr & 63;
  int b0 = bt*128, d0 = dt*128;
  int tid = threadIdx.x;
  int wv = tid >> 6, lane = tid & 63, l16 = lane & 15, quad = lane >> 4;
  int rl = lane >> 2, pl = lane & 3;   // DMA: 4 lanes per 64B row

  i32x4 zero = {0, 0, 0, 0};
  i32x4 acc[2][8];
  #pragma unroll
  for (int i = 0; i < 2; ++i)
    #pragma unroll
    for (int j = 0; j < 8; ++j) acc[i][j] = zero;

  const i8* Aqg = Aq + ((long)f*B_ + b0)*M_;
  const i8* Arg = Ar + ((long)f*B_ + b0)*M_;
  const i8* Bg  = cbT8 + ((long)f*D_ + d0)*M_;

  // per-wave DMA plan: 24 issues = 3 arrays x 8 windows(16 rows); wave takes 6.
  // lane fetches global chunk (pl ^ ((rl>>1)&3)) so LDS slot c' holds chunk c'^swz.
  const i8* gsrc[6];
  i8* lbase[6];
  int swz = (rl >> 1) & 3;
  #pragma unroll
  for (int j2 = 0; j2 < 6; ++j2){
    int i = j2*4 + wv;
    int t = i >> 3, j = i & 7;
    const i8* src = (t == 0) ? Aqg : (t == 1) ? Arg : Bg;
    gsrc[j2]  = src + (long)(j*16 + rl)*M_ + ((pl ^ swz) << 4);
    lbase[j2] = smem + t*8192 + j*1024;   // HW adds lane*16B
  }

  // prologue: issue kt=0 into buffer 0
  #pragma unroll
  for (int j2 = 0; j2 < 6; ++j2)
    gload_lds16(gsrc[j2], lbase[j2]);

  for (int kt = 0; kt < 8; ++kt){
    __syncthreads();   // drains buffer[kt&1]'s DMA; frees buffer[(kt+1)&1] reads
    if (kt < 7){
      int nb = (kt + 1) & 1, k0 = (kt + 1)*64;
      #pragma unroll
      for (int j2 = 0; j2 < 6; ++j2)
        gload_lds16(gsrc[j2] + k0, lbase[j2] + nb*SMSZ);
    }
    const i8* sb = smem + (kt & 1)*SMSZ;
    i32x4 aq[2], ar[2];
    #pragma unroll
    for (int rt = 0; rt < 2; ++rt){
      int row = wv*32 + rt*16 + l16;     // A[m=lane&15][k=quad*16+j]
      int c = (quad ^ ((row >> 1) & 3)) << 4;
      aq[rt] = *(const i32x4*)(sb +        row*64 + c);
      ar[rt] = *(const i32x4*)(sb + 8192 + row*64 + c);
    }
    #pragma unroll
    for (int ct = 0; ct < 8; ++ct){
      int rowB = ct*16 + l16;            // B[k=quad*16+j][n=lane&15] via B^T tile
      int c = (quad ^ ((rowB >> 1) & 3)) << 4;
      i32x4 bb = *(const i32x4*)(sb + 16384 + rowB*64 + c);
      i32x4 bb64;
      #pragma unroll
      for (int g = 0; g < 4; ++g)
        bb64[g] = (int)(((u32)bb[g] << 6) & 0xC0C0C0C0u);   // 64*c, exact for c=+-1
      #pragma unroll
      for (int rt = 0; rt < 2; ++rt){
        acc[rt][ct] = __builtin_amdgcn_mfma_i32_16x16x64_i8(aq[rt], bb64, acc[rt][ct], 0, 0, 0);
        acc[rt][ct] = __builtin_amdgcn_mfma_i32_16x16x64_i8(ar[rt], bb,   acc[rt][ct], 0, 0, 0);
      }
    }
  }

  // ballot epilogue: C/D layout col=lane&15, row=quad*4+reg. ballot bit(16q+t)
  // = sign at (row q*4+r, col ct*16+t). Word(row, pw) = 4 stitched 16b pieces.
  u32 mymiss = 0;
  int q3 = (lane >> 1) & 3, pw = lane & 1;
  #pragma unroll
  for (int rt = 0; rt < 2; ++rt){
    #pragma unroll
    for (int r = 0; r < 4; ++r){
      u64 lo[4], hi[4];
      #pragma unroll
      for (int c = 0; c < 4; ++c){
        lo[c] = __ballot(acc[rt][c][r]     < 0);
        hi[c] = __ballot(acc[rt][4 + c][r] < 0);
      }
      u64 word = 0;
      #pragma unroll
      for (int c = 0; c < 4; ++c){
        u64 sel = pw ? hi[c] : lo[c];
        word |= ((sel >> (16*q3)) & 0xFFFFull) << (16*c);
      }
      u32 flag = 0;
      if (lane < 8){
        int row = wv*32 + rt*16 + q3*4 + r;
        long addr = ((long)(b0 + row)*F_ + f)*DW_ + (dt*2 + pw);
        u64 old = estbits[addr];
        estbits[addr] = word;
        flag = (old != word) ? 1u : 0u;
      }
      mymiss |= (u32)(__ballot(flag != 0) != 0ull);
    }
  }
  if (lane == 0 && mymiss) atomicAnd(&fl->conv[iter], 0u);
}

// final: outcome = argmax_m |sim|, first-occurrence ties (exact integers).
__global__ __launch_bounds__(256) void k_outcome(
    const u64* __restrict__ estbits, const u64* __restrict__ cbbT,
    const Flags* __restrict__ fl, float* __restrict__ out){
  __shared__ u64 es[8][DW_];
  __shared__ int redv[4][8], redi[4][8];
  int f = blockIdx.y, b0 = blockIdx.x * 8;
  int tid = threadIdx.x, wv = tid >> 6, lane = tid & 63;
  for (int idx = tid; idx < 8*DW_; idx += 256){
    int bb = idx >> 7, w = idx & 127;
    es[bb][w] = estbits[((long)(b0 + bb)*F_ + f)*DW_ + w];
  }
  __syncthreads();
  const u64* cbf = cbbT + (long)f*DW_*M_;
  int m0 = tid, m1 = tid + 256;
  int acc0[8], acc1[8];
  #pragma unroll
  for (int bb = 0; bb < 8; ++bb){ acc0[bb] = 0; acc1[bb] = 0; }
  for (int w = 0; w < DW_; ++w){
    u64 c0 = cbf[(long)w*M_ + m0];
    u64 c1 = cbf[(long)w*M_ + m1];
    #pragma unroll
    for (int bb = 0; bb < 8; ++bb){
      u64 e = es[bb][w];
      acc0[bb] += (int)__popcll(e ^ c0);
      acc1[bb] += (int)__popcll(e ^ c1);
    }
  }
  int bv[8], bi[8];
  #pragma unroll
  for (int bb = 0; bb < 8; ++bb){
    int a0 = 4096 - acc0[bb]; if (a0 < 0) a0 = -a0;
    int a1 = 4096 - acc1[bb]; if (a1 < 0) a1 = -a1;
    bv[bb] = a0; bi[bb] = m0;
    if (a1 > a0){ bv[bb] = a1; bi[bb] = m1; }   // tie keeps lower m
  }
  for (int off = 32; off; off >>= 1){
    #pragma unroll
    for (int bb = 0; bb < 8; ++bb){
      int ov = __shfl_xor(bv[bb], off, 64);
      int oi = __shfl_xor(bi[bb], off, 64);
      if (ov > bv[bb] || (ov == bv[bb] && oi < bi[bb])){ bv[bb] = ov; bi[bb] = oi; }
    }
  }
  if (lane == 0)
    #pragma unroll
    for (int bb = 0; bb < 8; ++bb){ redv[wv][bb] = bv[bb]; redi[wv][bb] = bi[bb]; }
  __syncthreads();
  if (tid < 8){
    int v0 = redv[0][tid], i0 = redi[0][tid];
    for (int w = 1; w < 4; ++w){
      int v = redv[w][tid], i = redi[w][tid];
      if (v > v0 || (v == v0 && i < i0)){ v0 = v; i0 = i; }
    }
    out[(long)(b0 + tid)*F_ + f] = (float)i0;
  }
  if (blockIdx.x == 0 && f == 0 && tid == 0){
    int k = ITERS_;
    for (int j = 0; j < ITERS_; ++j) if (fl->conv[j]){ k = j + 1; break; }
    out[B_*F_] = (float)k;
  }
}

__global__ void k_unpack(const u64* __restrict__ estbits, float* __restrict__ out){
  long gid = (long)blockIdx.x*256 + threadIdx.x;   // over B*F*D/4
  int bf = (int)(gid >> 11);
  int d4 = (int)(gid & 2047);
  u64 word = estbits[(long)bf*DW_ + (d4 >> 4)];
  u32 nib = (u32)(word >> ((d4 & 15) * 4)) & 0xFu;
  long base = (long)(B_*F_ + 1) + (long)bf*D_ + (long)d4*4;
  out[base+0] = (nib & 1u) ? -1.0f : 1.0f;
  out[base+1] = (nib & 2u) ? -1.0f : 1.0f;
  out[base+2] = (nib & 4u) ? -1.0f : 1.0f;
  out[base+3] = (nib & 8u) ? -1.0f : 1.0f;
}

extern "C" void kernel_launch(void* const* d_in, const int* in_sizes, int n_in,
                              void* d_out, int out_size, void* d_ws, size_t ws_size,
                              hipStream_t stream){
  const float* input    = (const float*)d_in[0];
  const float* init_est = (const float*)d_in[1];
  const float* cb       = (const float*)d_in[2];
  char* ws   = (char*)d_ws;
  char* outc = (char*)d_out;

  size_t off = 0;
  Flags* fl = (Flags*)(ws); off = 1024;
  u64* tmp0    = (u64*)(ws + off); off += (size_t)F_*DW_*8;        // 4 KB
  off = (off + 1023) & ~size_t(1023);
  u64* inbits  = (u64*)(ws + off); off += (size_t)B_*DW_*8;        // 1 MB
  u64* estbits = (u64*)(ws + off); off += (size_t)B_*F_*DW_*8;     // 4 MB
  u64* cbbT    = (u64*)(ws + off); off += (size_t)F_*DW_*M_*8;     // 2 MB
  size_t big = (size_t)F_*D_*M_ + 2*(size_t)F_*B_*M_;              // 16 MB + 4 MB
  i8 *cbT8, *Aq, *Ar;
  if (ws_size >= off + big + 1024){
    cbT8 = (i8*)(ws + off); off += (size_t)F_*D_*M_;
    Aq   = (i8*)(ws + off); off += (size_t)F_*B_*M_;
    Ar   = (i8*)(ws + off); off += (size_t)F_*B_*M_;
  } else {
    // d_out is 33558529 float32 = 128.02 MiB; est chunk spans [16388, 134234116).
    // Park scratch high — only the final k_unpack overwrites it, after last use.
    cbT8 = (i8*)(outc + (80ull << 20));    // 80..96 MiB
    Aq   = (i8*)(outc + (100ull << 20));   // 100..102 MiB
    Ar   = (i8*)(outc + (104ull << 20));   // 104..106 MiB
  }

  k_bitify0<<<(F_*D_)/256, 256, 0, stream>>>(init_est, tmp0, fl);
  k_bcast<<<(B_*F_*DW_)/256, 256, 0, stream>>>(tmp0, estbits);
  k_bitify<<<(B_*(long)D_)/256, 256, 0, stream>>>(input, inbits);
  k_cb_prep<<<4096, 256, 0, stream>>>(cb, cbbT, cbT8);

  for (int it = 0; it < ITERS_; ++it){
    k_forward<<<2048, 128, 0, stream>>>(inbits, estbits, cbbT, Aq, Ar, fl, it);
    k_backward_mfma8<<<2048, 256, 0, stream>>>(Aq, Ar, cbT8, estbits, fl, it);
  }

  k_outcome<<<dim3(B_/8, F_), 256, 0, stream>>>(estbits, cbbT, fl, (float*)d_out);
  k_unpack<<<((long)B_*F_*D_/4)/256, 256, 0, stream>>>(estbits, (float*)d_out);
}